// Round 6
// baseline (281.712 us; speedup 1.0000x reference)
//
#include <hip/hip_runtime.h>

#define B_ 1024
#define S_ 100
#define E_ 128
#define A_ 256
#define H_ 4

typedef __attribute__((ext_vector_type(4))) float f32x4;
typedef __attribute__((ext_vector_type(8))) short s16x8;
typedef unsigned short u16;
typedef unsigned int u32;

__device__ __forceinline__ u16 f2bf(float x) {   // round-to-nearest-even
    u32 u = __builtin_bit_cast(u32, x);
    u32 r = u + 0x7FFFu + ((u >> 16) & 1u);
    return (u16)(r >> 16);
}
__device__ __forceinline__ float bf2f(u16 h) {
    u32 u = ((u32)h) << 16;
    return __builtin_bit_cast(float, u);
}
// truncation split: x = hi + lo exactly; hi bits in top half, bf16(lo) in bottom half
__device__ __forceinline__ u32 splitpack(float x) {
    u32 u = __builtin_bit_cast(u32, x);
    u32 hb = u & 0xFFFF0000u;
    float l = x - __builtin_bit_cast(float, hb);
    return hb | (__builtin_bit_cast(u32, l) >> 16);
}
__device__ __forceinline__ f32x4 mfma16(s16x8 a, s16x8 b, f32x4 c) {
    return __builtin_amdgcn_mfma_f32_16x16x32_bf16(a, b, c, 0, 0, 0);
}
__device__ __forceinline__ void split8(float4 a, float4 b, float msk, s16x8& hi, s16x8& lo) {
    float v[8] = { a.x, a.y, a.z, a.w, b.x, b.y, b.z, b.w };
    #pragma unroll
    for (int j = 0; j < 8; ++j) {
        float x = v[j] * msk;
        u32 u = __builtin_bit_cast(u32, x);
        u32 hb = u & 0xFFFF0000u;
        float l = x - __builtin_bit_cast(float, hb);
        hi[j] = (short)(u >> 16);
        lo[j] = (short)(__builtin_bit_cast(u32, l) >> 16);
    }
}
__device__ __forceinline__ s16x8 load_bfrag(const u16* wb, int t, int colbase, int lg, int lr) {
    return *reinterpret_cast<const s16x8*>(wb + ((((t * 4 + lg) * 256) + colbase + lr) << 3));
}

// ---------------- merged prep: blocks 0..1023 = unary softmax; 1024..1029 = weight split ----------------
__global__ __launch_bounds__(256) void prep_kernel(
    const float* __restrict__ key, const float* __restrict__ Wu,
    const float* __restrict__ Wq, const float* __restrict__ Wk,
    const float* __restrict__ Wv, const float* __restrict__ Wres,
    float* __restrict__ su, u16* __restrict__ wbuf)
{
    const int t = threadIdx.x;
    if (blockIdx.x >= 1024) {
        const int z = blockIdx.x - 1024;   // 0:q-hi 1:q-lo 2:k-hi 3:k-lo 4:v-hi 5:res-hi
        const float* src = (z < 2) ? Wq : (z < 4) ? Wk : (z == 4) ? Wv : Wres;
        const bool lo = (z == 1) || (z == 3);
        u16* dst = wbuf + (size_t)z * 32768;
        for (int i = t; i < E_ * A_; i += 256) {
            int e = i >> 8, col = i & 255;
            float x = src[i];
            u16 hi = f2bf(x);
            u16 outv = lo ? f2bf(x - bf2f(hi)) : hi;
            int ts = e >> 5, c = (e >> 3) & 3, j = e & 7;
            dst[(((ts * 4 + c) * 256 + col) << 3) + j] = outv;
        }
        return;
    }
    __shared__ float sm[S_ * H_];
    const int b = blockIdx.x;
    if (t < S_) {
        const float4* row = reinterpret_cast<const float4*>(key + ((size_t)b * S_ + t) * E_);
        const float4* wu4 = reinterpret_cast<const float4*>(Wu);
        float a0 = 0.f, a1 = 0.f, a2 = 0.f, a3 = 0.f;
        #pragma unroll 4
        for (int e4 = 0; e4 < E_ / 4; ++e4) {
            float4 kv = row[e4];
            float4 w0 = wu4[e4 * 4 + 0];
            float4 w1 = wu4[e4 * 4 + 1];
            float4 w2 = wu4[e4 * 4 + 2];
            float4 w3 = wu4[e4 * 4 + 3];
            a0 += kv.x * w0.x + kv.y * w1.x + kv.z * w2.x + kv.w * w3.x;
            a1 += kv.x * w0.y + kv.y * w1.y + kv.z * w2.y + kv.w * w3.y;
            a2 += kv.x * w0.z + kv.y * w1.z + kv.z * w2.z + kv.w * w3.z;
            a3 += kv.x * w0.w + kv.y * w1.w + kv.z * w2.w + kv.w * w3.w;
        }
        sm[t * 4 + 0] = a0; sm[t * 4 + 1] = a1;
        sm[t * 4 + 2] = a2; sm[t * 4 + 3] = a3;
    }
    __syncthreads();
    if (t < 128) {   // 32 lanes per head column
        const int hh = t >> 5, i = t & 31;
        float m = -1e30f;
        for (int s = i; s < S_; s += 32) m = fmaxf(m, sm[s * 4 + hh]);
        #pragma unroll
        for (int o = 1; o < 32; o <<= 1) m = fmaxf(m, __shfl_xor(m, o, 32));
        float sum = 0.f;
        for (int s = i; s < S_; s += 32) sum += __expf(sm[s * 4 + hh] - m);
        #pragma unroll
        for (int o = 1; o < 32; o <<= 1) sum += __shfl_xor(sum, o, 32);
        float inv = 1.f / sum;
        for (int s = i; s < S_; s += 32) sm[s * 4 + hh] = __expf(sm[s * 4 + hh] - m) * inv;
    }
    __syncthreads();
    for (int i2 = t; i2 < S_ * H_; i2 += 256)
        su[(size_t)b * (S_ * H_) + i2] = sm[i2];
}

// ---------------- fused kernel ----------------
__global__ __launch_bounds__(256, 2) void fused4_kernel(
    const float* __restrict__ query, const float* __restrict__ key, const float* __restrict__ value,
    const float* __restrict__ bres, const float* __restrict__ su,
    const u16* __restrict__ wbuf, float* __restrict__ out)
{
    __shared__ u32 smem[19872];               // 79488 B -> 2 blocks/CU
    u32* qc   = smem;                          // [112][68] packed (hi,lo)
    u32* kc   = smem + 7616;                   // [112][68]
    u16* vT   = (u16*)(smem + 15232);          // [64][128] bf16, xor-swz
    float* qmp  = (float*)(smem + 19328);      // [4][4][16] q col-sum partials
    float* rbuf = qmp + 256;                   // [112] r_j = qbar . k_j
    float* uwvb = rbuf + 112;                  // [64]
    float* subuf= uwvb + 64;                   // [112] su slice (tail zeroed)
    u16* pl = (u16*)smem;                      // P bf16 [112][136], aliases qc

    const int bid = blockIdx.x;
    // XCD-grouped swizzle: 4 heads of batch b on same XCD, close in time
    const int b = ((bid >> 5) << 3) | (bid & 7);
    const int h = (bid >> 3) & 3;
    const int g = h * B_ + b;
    const int tid = threadIdx.x;
    const int l = tid & 63, w = tid >> 6;
    const int lr = l & 15, lg = l >> 4;
    const int colb = h * 64;

    const float* Xq = query + (size_t)b * (S_ * E_);
    const float* Xk = key   + (size_t)b * (S_ * E_);
    const float* Xv = value + (size_t)b * (S_ * E_);

    const u16* wqh = wbuf;
    const u16* wql = wbuf + 32768;
    const u16* wkh = wbuf + 65536;
    const u16* wkl = wbuf + 98304;
    const u16* wvh = wbuf + 131072;
    const u16* wrh = wbuf + 163840;

    const int mt0 = w;
    const int mt1 = (w < 3) ? (w + 4) : 3;     // wave 3 duplicates tile 3 (branch-free)
    const int mt[2] = { mt0, mt1 };
    const float dupg = (w == 3) ? 0.f : 1.f;   // exclude dup tile from mean partials
    const f32x4 Z4 = { 0.f, 0.f, 0.f, 0.f };

    const int row0 = mt0 * 16 + lr, row1 = mt1 * 16 + lr;
    const float msk[2] = { (row0 < S_) ? 1.f : 0.f, (row1 < S_) ? 1.f : 0.f };
    const float* qp[2] = { Xq + (size_t)((row0 < S_) ? row0 : S_ - 1) * E_,
                           Xq + (size_t)((row1 < S_) ? row1 : S_ - 1) * E_ };
    const float* kp[2] = { Xk + (size_t)((row0 < S_) ? row0 : S_ - 1) * E_,
                           Xk + (size_t)((row1 < S_) ? row1 : S_ - 1) * E_ };
    const float* vp[2] = { Xv + (size_t)((row0 < S_) ? row0 : S_ - 1) * E_,
                           Xv + (size_t)((row1 < S_) ? row1 : S_ - 1) * E_ };

    // ---- issue q and k raw loads up front (latency hidden under q phase)
    float4 qr[2][4][2], kr[2][4][2];
    #pragma unroll
    for (int im = 0; im < 2; ++im)
        #pragma unroll
        for (int t = 0; t < 4; ++t) {
            qr[im][t][0] = *reinterpret_cast<const float4*>(qp[im] + t * 32 + lg * 8);
            qr[im][t][1] = *reinterpret_cast<const float4*>(qp[im] + t * 32 + lg * 8 + 4);
        }
    #pragma unroll
    for (int im = 0; im < 2; ++im)
        #pragma unroll
        for (int t = 0; t < 4; ++t) {
            kr[im][t][0] = *reinterpret_cast<const float4*>(kp[im] + t * 32 + lg * 8);
            kr[im][t][1] = *reinterpret_cast<const float4*>(kp[im] + t * 32 + lg * 8 + 4);
        }

    // ---- su slice -> LDS (tail zero); vT tail rows finite-zero (avoid stale NaN * 0)
    if (tid < S_) subuf[tid] = su[(size_t)g * S_ + tid];
    else if (tid < 112) subuf[tid] = 0.f;
    #pragma unroll
    for (int i = 0; i < 4; ++i) {
        int q = tid * 4 + i;
        int d = q & 63, k = 112 + (q >> 6);
        vT[d * 128 + (((k >> 3) ^ (d & 7)) << 3) + (k & 7)] = 0;
    }

    // ---- P1a: q-proj (3-term) + res-proj (2-term)
    s16x8 ah[2][4], al[2][4];
    #pragma unroll
    for (int im = 0; im < 2; ++im)
        #pragma unroll
        for (int t = 0; t < 4; ++t)
            split8(qr[im][t][0], qr[im][t][1], msk[im], ah[im][t], al[im][t]);

    f32x4 qa[2][4], ra[2][4];
    #pragma unroll
    for (int im = 0; im < 2; ++im)
        #pragma unroll
        for (int n = 0; n < 4; ++n) { qa[im][n] = Z4; ra[im][n] = Z4; }
    __builtin_amdgcn_s_setprio(1);
    #pragma unroll
    for (int n = 0; n < 4; ++n)
        #pragma unroll
        for (int t = 0; t < 4; ++t) {
            s16x8 bh = load_bfrag(wqh, t, colb + n * 16, lg, lr);
            s16x8 bl = load_bfrag(wql, t, colb + n * 16, lg, lr);
            s16x8 br = load_bfrag(wrh, t, colb + n * 16, lg, lr);
            #pragma unroll
            for (int im = 0; im < 2; ++im) {
                qa[im][n] = mfma16(ah[im][t], bh, qa[im][n]);
                qa[im][n] = mfma16(ah[im][t], bl, qa[im][n]);
                qa[im][n] = mfma16(al[im][t], bh, qa[im][n]);
                ra[im][n] = mfma16(ah[im][t], br, ra[im][n]);
                ra[im][n] = mfma16(al[im][t], br, ra[im][n]);
            }
        }
    __builtin_amdgcn_s_setprio(0);
    // qc write (uncentered) + q column-sum partials
    #pragma unroll
    for (int im = 0; im < 2; ++im)
        #pragma unroll
        for (int n = 0; n < 4; ++n)
            #pragma unroll
            for (int j = 0; j < 4; ++j)
                qc[(mt[im] * 16 + lg * 4 + j) * 68 + n * 16 + lr] = splitpack(qa[im][n][j]);
    #pragma unroll
    for (int n = 0; n < 4; ++n) {
        float p = 0.f;
        #pragma unroll
        for (int j = 0; j < 4; ++j) p += qa[0][n][j];
        float p1 = 0.f;
        #pragma unroll
        for (int j = 0; j < 4; ++j) p1 += qa[1][n][j];
        p += dupg * p1;
        p += __shfl_xor(p, 16, 64);
        p += __shfl_xor(p, 32, 64);
        if (lg == 0) qmp[(w * 4 + n) * 16 + lr] = p;
    }

    // ---- issue v raw loads, then k split + MFMA (v latency hides under k phase)
    float4 vr[2][4][2];
    #pragma unroll
    for (int im = 0; im < 2; ++im)
        #pragma unroll
        for (int t = 0; t < 4; ++t) {
            vr[im][t][0] = *reinterpret_cast<const float4*>(vp[im] + t * 32 + lg * 8);
            vr[im][t][1] = *reinterpret_cast<const float4*>(vp[im] + t * 32 + lg * 8 + 4);
        }
    #pragma unroll
    for (int im = 0; im < 2; ++im)
        #pragma unroll
        for (int t = 0; t < 4; ++t)
            split8(kr[im][t][0], kr[im][t][1], msk[im], ah[im][t], al[im][t]);

    f32x4 ka[2][4];
    #pragma unroll
    for (int im = 0; im < 2; ++im)
        #pragma unroll
        for (int n = 0; n < 4; ++n) ka[im][n] = Z4;
    __builtin_amdgcn_s_setprio(1);
    #pragma unroll
    for (int n = 0; n < 4; ++n)
        #pragma unroll
        for (int t = 0; t < 4; ++t) {
            s16x8 bh = load_bfrag(wkh, t, colb + n * 16, lg, lr);
            s16x8 bl = load_bfrag(wkl, t, colb + n * 16, lg, lr);
            #pragma unroll
            for (int im = 0; im < 2; ++im) {
                ka[im][n] = mfma16(ah[im][t], bh, ka[im][n]);
                ka[im][n] = mfma16(ah[im][t], bl, ka[im][n]);
                ka[im][n] = mfma16(al[im][t], bh, ka[im][n]);
            }
        }
    __builtin_amdgcn_s_setprio(0);
    #pragma unroll
    for (int im = 0; im < 2; ++im)
        #pragma unroll
        for (int n = 0; n < 4; ++n)
            #pragma unroll
            for (int j = 0; j < 4; ++j)
                kc[(mt[im] * 16 + lg * 4 + j) * 68 + n * 16 + lr] = splitpack(ka[im][n][j]);

    __syncthreads();                           // B1: qmp/subuf visible

    // ---- r_j = qbar . k_j  (per own k-rows, from live ka)
    {
        float qbar[4];
        #pragma unroll
        for (int n = 0; n < 4; ++n) {
            float s = 0.f;
            #pragma unroll
            for (int wv = 0; wv < 4; ++wv) s += qmp[(wv * 4 + n) * 16 + lr];
            qbar[n] = s * (1.f / S_);
        }
        #pragma unroll
        for (int im = 0; im < 2; ++im) {
            float pr[4];
            #pragma unroll
            for (int j = 0; j < 4; ++j) {
                float s = 0.f;
                #pragma unroll
                for (int n = 0; n < 4; ++n) s += qbar[n] * ka[im][n][j];
                pr[j] = s;
            }
            #pragma unroll
            for (int o = 1; o < 16; o <<= 1)
                #pragma unroll
                for (int j = 0; j < 4; ++j) pr[j] += __shfl_xor(pr[j], o, 16);
            if (lr == 0)
                #pragma unroll
                for (int j = 0; j < 4; ++j) rbuf[mt[im] * 16 + lg * 4 + j] = pr[j];
        }
    }

    // ---- P1c: v-proj (2-term) -> vT
    #pragma unroll
    for (int im = 0; im < 2; ++im)
        #pragma unroll
        for (int t = 0; t < 4; ++t)
            split8(vr[im][t][0], vr[im][t][1], msk[im], ah[im][t], al[im][t]);
    {
        f32x4 va[2][4];
        #pragma unroll
        for (int im = 0; im < 2; ++im)
            #pragma unroll
            for (int n = 0; n < 4; ++n) va[im][n] = Z4;
        __builtin_amdgcn_s_setprio(1);
        #pragma unroll
        for (int n = 0; n < 4; ++n)
            #pragma unroll
            for (int t = 0; t < 4; ++t) {
                s16x8 bh = load_bfrag(wvh, t, colb + n * 16, lg, lr);
                #pragma unroll
                for (int im = 0; im < 2; ++im) {
                    va[im][n] = mfma16(ah[im][t], bh, va[im][n]);
                    va[im][n] = mfma16(al[im][t], bh, va[im][n]);
                }
            }
        __builtin_amdgcn_s_setprio(0);
        #pragma unroll
        for (int im = 0; im < 2; ++im)
            #pragma unroll
            for (int n = 0; n < 4; ++n)
                #pragma unroll
                for (int j = 0; j < 4; ++j) {
                    int r = mt[im] * 16 + lg * 4 + j;
                    int d = n * 16 + lr;
                    vT[d * 128 + (((r >> 3) ^ (d & 7)) << 3) + (r & 7)] = f2bf(va[im][n][j]);
                }
    }
    __syncthreads();                           // B2: qc/kc/vT/rbuf all visible

    // ---- pair = q @ k^T (3-term split), logits in registers
    s16x8 qhf[2][2], qlf[2][2];
    #pragma unroll
    for (int im = 0; im < 2; ++im)
        #pragma unroll
        for (int t = 0; t < 2; ++t) {
            int base = (mt[im] * 16 + lr) * 68 + t * 32 + lg * 8;
            uint4 u0 = *reinterpret_cast<const uint4*>(qc + base);
            uint4 u1 = *reinterpret_cast<const uint4*>(qc + base + 4);
            u32 uu[8] = { u0.x, u0.y, u0.z, u0.w, u1.x, u1.y, u1.z, u1.w };
            s16x8 hi, lo;
            #pragma unroll
            for (int j = 0; j < 8; ++j) { hi[j] = (short)(uu[j] >> 16); lo[j] = (short)(uu[j] & 0xFFFFu); }
            qhf[im][t] = hi; qlf[im][t] = lo;
        }
    f32x4 z[2][7];
    #pragma unroll
    for (int im = 0; im < 2; ++im)
        #pragma unroll
        for (int n = 0; n < 7; ++n) z[im][n] = Z4;
    __builtin_amdgcn_s_setprio(1);
    #pragma unroll
    for (int n = 0; n < 7; ++n)
        #pragma unroll
        for (int t = 0; t < 2; ++t) {
            int base = (n * 16 + lr) * 68 + t * 32 + lg * 8;
            uint4 u0 = *reinterpret_cast<const uint4*>(kc + base);
            uint4 u1 = *reinterpret_cast<const uint4*>(kc + base + 4);
            u32 uu[8] = { u0.x, u0.y, u0.z, u0.w, u1.x, u1.y, u1.z, u1.w };
            s16x8 bh, bl;
            #pragma unroll
            for (int j = 0; j < 8; ++j) { bh[j] = (short)(uu[j] >> 16); bl[j] = (short)(uu[j] & 0xFFFFu); }
            #pragma unroll
            for (int im = 0; im < 2; ++im) {
                z[im][n] = mfma16(qhf[im][t], bh, z[im][n]);
                z[im][n] = mfma16(qhf[im][t], bl, z[im][n]);
                z[im][n] = mfma16(qlf[im][t], bh, z[im][n]);
            }
        }
    __builtin_amdgcn_s_setprio(0);

    // ---- uwv = su . v, spread over all waves (wave w owns d = w*16+lr; lg splits k)
    {
        const int d = w * 16 + lr;
        float acc = 0.f;
        #pragma unroll
        for (int c = 0; c < 3; ++c) {
            int k8 = lg + c * 4;               // chunks 0..11
            s16x8 vv = *reinterpret_cast<const s16x8*>(vT + d * 128 + ((k8 ^ (d & 7)) << 3));
            #pragma unroll
            for (int j = 0; j < 8; ++j) acc += subuf[k8 * 8 + j] * bf2f((u16)vv[j]);
        }
        if (lg == 0) {                         // chunk 12 (k=96..103; subuf[100..]=0)
            s16x8 vv = *reinterpret_cast<const s16x8*>(vT + d * 128 + ((12 ^ (d & 7)) << 3));
            #pragma unroll
            for (int j = 0; j < 8; ++j) acc += subuf[96 + j] * bf2f((u16)vv[j]);
        }
        acc += __shfl_xor(acc, 16, 64);
        acc += __shfl_xor(acc, 32, 64);
        if (lg == 0) uwvb[d] = acc;
    }

    // ---- subtract r_j, mask invalid cols, softmax over k (in-register)
    #pragma unroll
    for (int im = 0; im < 2; ++im) {
        #pragma unroll
        for (int n = 0; n < 7; ++n) {
            float rr = rbuf[n * 16 + lr];
            #pragma unroll
            for (int j = 0; j < 4; ++j) z[im][n][j] -= rr;
        }
        if (lr >= 4) {                         // cols 100..111 invalid
            f32x4 NEG = { -1e30f, -1e30f, -1e30f, -1e30f };
            z[im][6] = NEG;
        }
        #pragma unroll
        for (int j = 0; j < 4; ++j) {
            float m = z[im][0][j];
            #pragma unroll
            for (int n = 1; n < 7; ++n) m = fmaxf(m, z[im][n][j]);
            #pragma unroll
            for (int o = 1; o < 16; o <<= 1) m = fmaxf(m, __shfl_xor(m, o, 16));
            float s = 0.f;
            #pragma unroll
            for (int n = 0; n < 7; ++n) { float p = __expf(z[im][n][j] - m); z[im][n][j] = p; s += p; }
            #pragma unroll
            for (int o = 1; o < 16; o <<= 1) s += __shfl_xor(s, o, 16);
            float inv = 1.f / s;
            #pragma unroll
            for (int n = 0; n < 7; ++n) z[im][n][j] *= inv;
        }
    }
    __syncthreads();                           // B3: all qc/kc reads done (pl aliases qc)

    // ---- write P (bf16); cols 112..127 zeroed
    #pragma unroll
    for (int im = 0; im < 2; ++im) {
        #pragma unroll
        for (int n = 0; n < 7; ++n)
            #pragma unroll
            for (int j = 0; j < 4; ++j) {
                int row = mt[im] * 16 + lg * 4 + j;
                pl[row * 136 + n * 16 + lr] = f2bf(z[im][n][j]);
            }
        #pragma unroll
        for (int j = 0; j < 4; ++j) {
            int row = mt[im] * 16 + lg * 4 + j;
            pl[row * 136 + 112 + lr] = 0;
        }
    }
    __syncthreads();                           // B4: P + vT ready

    // ---- PV (1-term bf16) + epilogue
    s16x8 pa[2][4];
    #pragma unroll
    for (int im = 0; im < 2; ++im)
        #pragma unroll
        for (int t = 0; t < 4; ++t)
            pa[im][t] = *reinterpret_cast<const s16x8*>(pl + (mt[im] * 16 + lr) * 136 + t * 32 + lg * 8);
    f32x4 pv[2][4];
    #pragma unroll
    for (int im = 0; im < 2; ++im)
        #pragma unroll
        for (int n = 0; n < 4; ++n) pv[im][n] = Z4;
    __builtin_amdgcn_s_setprio(1);
    #pragma unroll
    for (int n = 0; n < 4; ++n)
        #pragma unroll
        for (int t = 0; t < 4; ++t) {
            int d = n * 16 + lr;
            s16x8 bv = *reinterpret_cast<const s16x8*>(vT + d * 128 + ((((t * 4 + lg)) ^ (d & 7)) << 3));
            #pragma unroll
            for (int im = 0; im < 2; ++im)
                pv[im][n] = mfma16(pa[im][t], bv, pv[im][n]);
        }
    __builtin_amdgcn_s_setprio(0);

    float bv4[4];
    #pragma unroll
    for (int n = 0; n < 4; ++n) bv4[n] = bres[colb + n * 16 + lr];
    #pragma unroll
    for (int im = 0; im < 2; ++im)
        #pragma unroll
        for (int n = 0; n < 4; ++n) {
            int d = n * 16 + lr;
            float add = bv4[n] + uwvb[d];
            #pragma unroll
            for (int j = 0; j < 4; ++j) {
                int row = mt[im] * 16 + lg * 4 + j;
                if (row < S_)
                    out[((size_t)b * S_ + row) * A_ + colb + d] = ra[im][n][j] + pv[im][n][j] + add;
            }
        }
}

extern "C" void kernel_launch(void* const* d_in, const int* in_sizes, int n_in,
                              void* d_out, int out_size, void* d_ws, size_t ws_size,
                              hipStream_t stream) {
    const float* query = (const float*)d_in[0];
    const float* key   = (const float*)d_in[1];
    const float* value = (const float*)d_in[2];
    const float* Wq    = (const float*)d_in[3];
    const float* Wk    = (const float*)d_in[4];
    const float* Wv    = (const float*)d_in[5];
    const float* Wu    = (const float*)d_in[6];
    const float* Wres  = (const float*)d_in[7];
    const float* bres  = (const float*)d_in[8];
    float* out = (float*)d_out;

    float* su  = (float*)d_ws;                          // 1.6384 MB
    u16*  wbuf = (u16*)((char*)d_ws + 1638400);         // 6 * 64 KB split weights

    prep_kernel<<<1030, 256, 0, stream>>>(key, Wu, Wq, Wk, Wv, Wres, su, wbuf);
    fused4_kernel<<<B_ * H_, 256, 0, stream>>>(query, key, value, bres, su, wbuf, out);
}

// Round 8
// 275.222 us; speedup vs baseline: 1.0236x; 1.0236x over previous
//
#include <hip/hip_runtime.h>

#define B_ 1024
#define S_ 100
#define E_ 128
#define A_ 256
#define H_ 4

typedef __attribute__((ext_vector_type(4))) float f32x4;
typedef __attribute__((ext_vector_type(8))) short s16x8;
typedef __attribute__((ext_vector_type(4))) unsigned int u32x4;
typedef unsigned short u16;
typedef unsigned int u32;

__device__ __forceinline__ u16 f2bf(float x) {   // round-to-nearest-even
    u32 u = __builtin_bit_cast(u32, x);
    u32 r = u + 0x7FFFu + ((u >> 16) & 1u);
    return (u16)(r >> 16);
}
__device__ __forceinline__ float bf2f(u16 h) {
    u32 u = ((u32)h) << 16;
    return __builtin_bit_cast(float, u);
}
// pack trunc-bf16 of two floats into one u32 (x1 in high half) — 1 v_perm
__device__ __forceinline__ u32 permpack(float x1, float x0) {
    return __builtin_amdgcn_perm(__builtin_bit_cast(u32, x1),
                                 __builtin_bit_cast(u32, x0), 0x07060302u);
}
// truncation split: x = hi + lo exactly; per-elem packed u32 (hi<<16 | bf16(lo))
__device__ __forceinline__ u32 splitpack(float x) {
    u32 u = __builtin_bit_cast(u32, x);
    u32 hb = u & 0xFFFF0000u;
    float l = x - __builtin_bit_cast(float, hb);
    return hb | (__builtin_bit_cast(u32, l) >> 16);
}
__device__ __forceinline__ f32x4 mfma16(s16x8 a, s16x8 b, f32x4 c) {
    return __builtin_amdgcn_mfma_f32_16x16x32_bf16(a, b, c, 0, 0, 0);
}
// trunc split of 8 floats (masked) into hi/lo bf16 frags via v_perm.
// Value-identical to the round-6 scalar split8: x = v*msk; hi = trunc16(x);
// lo = trunc16(x - hi).  msk=0 -> exact zeros in both frags.
__device__ __forceinline__ void split8pm(float4 a, float4 b, float msk, s16x8& hi, s16x8& lo) {
    float v[8] = { a.x, a.y, a.z, a.w, b.x, b.y, b.z, b.w };
    u32x4 H, L;
    #pragma unroll
    for (int m = 0; m < 4; ++m) {
        float x0 = v[2 * m] * msk, x1 = v[2 * m + 1] * msk;
        u32 h = permpack(x1, x0);
        float h0 = __builtin_bit_cast(float, h << 16);
        float h1 = __builtin_bit_cast(float, h & 0xFFFF0000u);
        u32 lw = permpack(x1 - h1, x0 - h0);
        H[m] = h; L[m] = lw;
    }
    hi = __builtin_bit_cast(s16x8, H);
    lo = __builtin_bit_cast(s16x8, L);
}
// unpack 8 packed (hi|lo) u32 -> hi-frag + lo-frag (8 perms).
// Value-identical to round-6's manual shift/mask unpack.
__device__ __forceinline__ void unpack16(const u32* base, s16x8& hi, s16x8& lo) {
    uint4 u0 = *reinterpret_cast<const uint4*>(base);
    uint4 u1 = *reinterpret_cast<const uint4*>(base + 4);
    u32 p[8] = { u0.x, u0.y, u0.z, u0.w, u1.x, u1.y, u1.z, u1.w };
    u32x4 H, L;
    #pragma unroll
    for (int m = 0; m < 4; ++m) {
        H[m] = __builtin_amdgcn_perm(p[2 * m + 1], p[2 * m], 0x07060302u);
        L[m] = __builtin_amdgcn_perm(p[2 * m + 1], p[2 * m], 0x05040100u);
    }
    hi = __builtin_bit_cast(s16x8, H);
    lo = __builtin_bit_cast(s16x8, L);
}
__device__ __forceinline__ s16x8 load_bfrag(const u16* wb, int t, int colbase, int lg, int lr) {
    return *reinterpret_cast<const s16x8*>(wb + ((((t * 4 + lg) * 256) + colbase + lr) << 3));
}

// ---------------- merged prep: blocks 0..1023 = unary softmax; 1024..1029 = weight split ----------------
__global__ __launch_bounds__(256) void prep_kernel(
    const float* __restrict__ key, const float* __restrict__ Wu,
    const float* __restrict__ Wq, const float* __restrict__ Wk,
    const float* __restrict__ Wv, const float* __restrict__ Wres,
    float* __restrict__ su, u16* __restrict__ wbuf)
{
    const int t = threadIdx.x;
    if (blockIdx.x >= 1024) {
        const int z = blockIdx.x - 1024;   // 0:q-hi 1:q-lo 2:k-hi 3:k-lo 4:v-hi 5:res-hi
        const float* src = (z < 2) ? Wq : (z < 4) ? Wk : (z == 4) ? Wv : Wres;
        const bool lo = (z == 1) || (z == 3);
        u16* dst = wbuf + (size_t)z * 32768;
        for (int i = t; i < E_ * A_; i += 256) {
            int e = i >> 8, col = i & 255;
            float x = src[i];
            u16 hi = f2bf(x);
            u16 outv = lo ? f2bf(x - bf2f(hi)) : hi;
            int ts = e >> 5, c = (e >> 3) & 3, j = e & 7;
            dst[(((ts * 4 + c) * 256 + col) << 3) + j] = outv;
        }
        return;
    }
    __shared__ float sm[S_ * H_];
    const int b = blockIdx.x;
    if (t < S_) {
        const float4* row = reinterpret_cast<const float4*>(key + ((size_t)b * S_ + t) * E_);
        const float4* wu4 = reinterpret_cast<const float4*>(Wu);
        float a0 = 0.f, a1 = 0.f, a2 = 0.f, a3 = 0.f;
        #pragma unroll 4
        for (int e4 = 0; e4 < E_ / 4; ++e4) {
            float4 kv = row[e4];
            float4 w0 = wu4[e4 * 4 + 0];
            float4 w1 = wu4[e4 * 4 + 1];
            float4 w2 = wu4[e4 * 4 + 2];
            float4 w3 = wu4[e4 * 4 + 3];
            a0 += kv.x * w0.x + kv.y * w1.x + kv.z * w2.x + kv.w * w3.x;
            a1 += kv.x * w0.y + kv.y * w1.y + kv.z * w2.y + kv.w * w3.y;
            a2 += kv.x * w0.z + kv.y * w1.z + kv.z * w2.z + kv.w * w3.z;
            a3 += kv.x * w0.w + kv.y * w1.w + kv.z * w2.w + kv.w * w3.w;
        }
        sm[t * 4 + 0] = a0; sm[t * 4 + 1] = a1;
        sm[t * 4 + 2] = a2; sm[t * 4 + 3] = a3;
    }
    __syncthreads();
    if (t < 128) {   // 32 lanes per head column
        const int hh = t >> 5, i = t & 31;
        float m = -1e30f;
        for (int s = i; s < S_; s += 32) m = fmaxf(m, sm[s * 4 + hh]);
        #pragma unroll
        for (int o = 1; o < 32; o <<= 1) m = fmaxf(m, __shfl_xor(m, o, 32));
        float sum = 0.f;
        for (int s = i; s < S_; s += 32) sum += __expf(sm[s * 4 + hh] - m);
        #pragma unroll
        for (int o = 1; o < 32; o <<= 1) sum += __shfl_xor(sum, o, 32);
        float inv = 1.f / sum;
        for (int s = i; s < S_; s += 32) sm[s * 4 + hh] = __expf(sm[s * 4 + hh] - m) * inv;
    }
    __syncthreads();
    for (int i2 = t; i2 < S_ * H_; i2 += 256)
        su[(size_t)b * (S_ * H_) + i2] = sm[i2];
}

// ---------------- fused kernel (round-6 structure; perm packing; res 1-term) ----------------
__global__ __launch_bounds__(256, 2) void fused6_kernel(
    const float* __restrict__ query, const float* __restrict__ key, const float* __restrict__ value,
    const float* __restrict__ bres, const float* __restrict__ su,
    const u16* __restrict__ wbuf, float* __restrict__ out)
{
    __shared__ u32 smem[19872];               // 79488 B -> 2 blocks/CU
    u32* qc   = smem;                          // [112][68] packed (hi,lo)
    u32* kc   = smem + 7616;                   // [112][68]
    u16* vT   = (u16*)(smem + 15232);          // [64][128] bf16, xor-swz
    float* qmp  = (float*)(smem + 19328);      // [4][4][16] q col-sum partials
    float* rbuf = qmp + 256;                   // [112] r_j = qbar . k_j
    float* uwvb = rbuf + 112;                  // [64]
    float* subuf= uwvb + 64;                   // [112] su slice (tail zeroed)
    u16* pl = (u16*)smem;                      // P bf16 [112][136], aliases qc

    const int bid = blockIdx.x;
    // XCD-grouped swizzle: 4 heads of batch b on same XCD, close in time
    const int b = ((bid >> 5) << 3) | (bid & 7);
    const int h = (bid >> 3) & 3;
    const int g = h * B_ + b;
    const int tid = threadIdx.x;
    const int l = tid & 63, w = tid >> 6;
    const int lr = l & 15, lg = l >> 4;
    const int colb = h * 64;

    const float* Xq = query + (size_t)b * (S_ * E_);
    const float* Xk = key   + (size_t)b * (S_ * E_);
    const float* Xv = value + (size_t)b * (S_ * E_);

    const u16* wqh = wbuf;
    const u16* wql = wbuf + 32768;
    const u16* wkh = wbuf + 65536;
    const u16* wkl = wbuf + 98304;
    const u16* wvh = wbuf + 131072;
    const u16* wrh = wbuf + 163840;

    const int mt0 = w;
    const int mt1 = (w < 3) ? (w + 4) : 3;     // wave 3 duplicates tile 3 (branch-free)
    const int mt[2] = { mt0, mt1 };
    const float dupg = (w == 3) ? 0.f : 1.f;   // exclude dup tile from mean partials
    const f32x4 Z4 = { 0.f, 0.f, 0.f, 0.f };

    const int row0 = mt0 * 16 + lr, row1 = mt1 * 16 + lr;
    const float msk[2] = { (row0 < S_) ? 1.f : 0.f, (row1 < S_) ? 1.f : 0.f };
    const float* qp[2] = { Xq + (size_t)((row0 < S_) ? row0 : S_ - 1) * E_,
                           Xq + (size_t)((row1 < S_) ? row1 : S_ - 1) * E_ };
    const float* kp[2] = { Xk + (size_t)((row0 < S_) ? row0 : S_ - 1) * E_,
                           Xk + (size_t)((row1 < S_) ? row1 : S_ - 1) * E_ };
    const float* vp[2] = { Xv + (size_t)((row0 < S_) ? row0 : S_ - 1) * E_,
                           Xv + (size_t)((row1 < S_) ? row1 : S_ - 1) * E_ };

    // ---- issue q and k raw loads up front (latency hidden under q phase)
    float4 qr[2][4][2], kr[2][4][2];
    #pragma unroll
    for (int im = 0; im < 2; ++im)
        #pragma unroll
        for (int t = 0; t < 4; ++t) {
            qr[im][t][0] = *reinterpret_cast<const float4*>(qp[im] + t * 32 + lg * 8);
            qr[im][t][1] = *reinterpret_cast<const float4*>(qp[im] + t * 32 + lg * 8 + 4);
        }
    #pragma unroll
    for (int im = 0; im < 2; ++im)
        #pragma unroll
        for (int t = 0; t < 4; ++t) {
            kr[im][t][0] = *reinterpret_cast<const float4*>(kp[im] + t * 32 + lg * 8);
            kr[im][t][1] = *reinterpret_cast<const float4*>(kp[im] + t * 32 + lg * 8 + 4);
        }

    // ---- su slice -> LDS (tail zero); vT tail rows zero
    if (tid < S_) subuf[tid] = su[(size_t)g * S_ + tid];
    else if (tid < 112) subuf[tid] = 0.f;
    #pragma unroll
    for (int i = 0; i < 4; ++i) {
        int q = tid * 4 + i;
        int d = q & 63, k = 112 + (q >> 6);
        vT[d * 128 + (((k >> 3) ^ (d & 7)) << 3) + (k & 7)] = 0;
    }

    // ---- P1a: q-proj (3-term) + res-proj (1-term, hi*hi)
    s16x8 ah[2][4], al[2][4];
    #pragma unroll
    for (int im = 0; im < 2; ++im)
        #pragma unroll
        for (int t = 0; t < 4; ++t)
            split8pm(qr[im][t][0], qr[im][t][1], msk[im], ah[im][t], al[im][t]);

    f32x4 qa[2][4], ra[2][4];
    #pragma unroll
    for (int im = 0; im < 2; ++im)
        #pragma unroll
        for (int n = 0; n < 4; ++n) { qa[im][n] = Z4; ra[im][n] = Z4; }
    __builtin_amdgcn_s_setprio(1);
    #pragma unroll
    for (int n = 0; n < 4; ++n)
        #pragma unroll
        for (int t = 0; t < 4; ++t) {
            s16x8 bh = load_bfrag(wqh, t, colb + n * 16, lg, lr);
            s16x8 bl = load_bfrag(wql, t, colb + n * 16, lg, lr);
            s16x8 br = load_bfrag(wrh, t, colb + n * 16, lg, lr);
            #pragma unroll
            for (int im = 0; im < 2; ++im) {
                qa[im][n] = mfma16(ah[im][t], bh, qa[im][n]);
                qa[im][n] = mfma16(ah[im][t], bl, qa[im][n]);
                qa[im][n] = mfma16(al[im][t], bh, qa[im][n]);
                ra[im][n] = mfma16(ah[im][t], br, ra[im][n]);
            }
        }
    __builtin_amdgcn_s_setprio(0);
    // qc write (uncentered) + q column-sum partials (pad rows are exact zeros)
    #pragma unroll
    for (int im = 0; im < 2; ++im)
        #pragma unroll
        for (int n = 0; n < 4; ++n)
            #pragma unroll
            for (int j = 0; j < 4; ++j)
                qc[(mt[im] * 16 + lg * 4 + j) * 68 + n * 16 + lr] = splitpack(qa[im][n][j]);
    #pragma unroll
    for (int n = 0; n < 4; ++n) {
        float p = 0.f;
        #pragma unroll
        for (int j = 0; j < 4; ++j) p += qa[0][n][j];
        float p1 = 0.f;
        #pragma unroll
        for (int j = 0; j < 4; ++j) p1 += qa[1][n][j];
        p += dupg * p1;
        p += __shfl_xor(p, 16, 64);
        p += __shfl_xor(p, 32, 64);
        if (lg == 0) qmp[(w * 4 + n) * 16 + lr] = p;
    }

    // ---- issue v raw loads, then k split + MFMA (3-term)
    float4 vr[2][4][2];
    #pragma unroll
    for (int im = 0; im < 2; ++im)
        #pragma unroll
        for (int t = 0; t < 4; ++t) {
            vr[im][t][0] = *reinterpret_cast<const float4*>(vp[im] + t * 32 + lg * 8);
            vr[im][t][1] = *reinterpret_cast<const float4*>(vp[im] + t * 32 + lg * 8 + 4);
        }
    #pragma unroll
    for (int im = 0; im < 2; ++im)
        #pragma unroll
        for (int t = 0; t < 4; ++t)
            split8pm(kr[im][t][0], kr[im][t][1], msk[im], ah[im][t], al[im][t]);

    f32x4 ka[2][4];
    #pragma unroll
    for (int im = 0; im < 2; ++im)
        #pragma unroll
        for (int n = 0; n < 4; ++n) ka[im][n] = Z4;
    __builtin_amdgcn_s_setprio(1);
    #pragma unroll
    for (int n = 0; n < 4; ++n)
        #pragma unroll
        for (int t = 0; t < 4; ++t) {
            s16x8 bh = load_bfrag(wkh, t, colb + n * 16, lg, lr);
            s16x8 bl = load_bfrag(wkl, t, colb + n * 16, lg, lr);
            #pragma unroll
            for (int im = 0; im < 2; ++im) {
                ka[im][n] = mfma16(ah[im][t], bh, ka[im][n]);
                ka[im][n] = mfma16(ah[im][t], bl, ka[im][n]);
                ka[im][n] = mfma16(al[im][t], bh, ka[im][n]);
            }
        }
    __builtin_amdgcn_s_setprio(0);
    #pragma unroll
    for (int im = 0; im < 2; ++im)
        #pragma unroll
        for (int n = 0; n < 4; ++n)
            #pragma unroll
            for (int j = 0; j < 4; ++j)
                kc[(mt[im] * 16 + lg * 4 + j) * 68 + n * 16 + lr] = splitpack(ka[im][n][j]);

    __syncthreads();                           // B1: qmp/subuf visible

    // ---- r_j = qbar . k_j (per own k-rows, from live ka)
    {
        float qbar[4];
        #pragma unroll
        for (int n = 0; n < 4; ++n) {
            float s = 0.f;
            #pragma unroll
            for (int wv = 0; wv < 4; ++wv) s += qmp[(wv * 4 + n) * 16 + lr];
            qbar[n] = s * (1.f / S_);
        }
        #pragma unroll
        for (int im = 0; im < 2; ++im) {
            float pr[4];
            #pragma unroll
            for (int j = 0; j < 4; ++j) {
                float s = 0.f;
                #pragma unroll
                for (int n = 0; n < 4; ++n) s += qbar[n] * ka[im][n][j];
                pr[j] = s;
            }
            #pragma unroll
            for (int o = 1; o < 16; o <<= 1)
                #pragma unroll
                for (int j = 0; j < 4; ++j) pr[j] += __shfl_xor(pr[j], o, 16);
            if (lr == 0)
                #pragma unroll
                for (int j = 0; j < 4; ++j) rbuf[mt[im] * 16 + lg * 4 + j] = pr[j];
        }
    }

    // ---- P1c: v-proj (2-term) -> vT (transposed, swizzled)
    #pragma unroll
    for (int im = 0; im < 2; ++im)
        #pragma unroll
        for (int t = 0; t < 4; ++t)
            split8pm(vr[im][t][0], vr[im][t][1], msk[im], ah[im][t], al[im][t]);
    {
        f32x4 va[2][4];
        #pragma unroll
        for (int im = 0; im < 2; ++im)
            #pragma unroll
            for (int n = 0; n < 4; ++n) va[im][n] = Z4;
        __builtin_amdgcn_s_setprio(1);
        #pragma unroll
        for (int n = 0; n < 4; ++n)
            #pragma unroll
            for (int t = 0; t < 4; ++t) {
                s16x8 bh = load_bfrag(wvh, t, colb + n * 16, lg, lr);
                #pragma unroll
                for (int im = 0; im < 2; ++im) {
                    va[im][n] = mfma16(ah[im][t], bh, va[im][n]);
                    va[im][n] = mfma16(al[im][t], bh, va[im][n]);
                }
            }
        __builtin_amdgcn_s_setprio(0);
        #pragma unroll
        for (int im = 0; im < 2; ++im)
            #pragma unroll
            for (int n = 0; n < 4; ++n)
                #pragma unroll
                for (int j = 0; j < 4; ++j) {
                    int r = mt[im] * 16 + lg * 4 + j;
                    int d = n * 16 + lr;
                    vT[d * 128 + (((r >> 3) ^ (d & 7)) << 3) + (r & 7)] = f2bf(va[im][n][j]);
                }
    }
    __syncthreads();                           // B2: qc/kc/vT/rbuf all visible

    // ---- pair = q @ k^T (3-term split), logits in registers
    s16x8 qhf[2][2], qlf[2][2];
    #pragma unroll
    for (int im = 0; im < 2; ++im)
        #pragma unroll
        for (int t = 0; t < 2; ++t)
            unpack16(qc + (mt[im] * 16 + lr) * 68 + t * 32 + lg * 8, qhf[im][t], qlf[im][t]);
    f32x4 z[2][7];
    #pragma unroll
    for (int im = 0; im < 2; ++im)
        #pragma unroll
        for (int n = 0; n < 7; ++n) z[im][n] = Z4;
    __builtin_amdgcn_s_setprio(1);
    #pragma unroll
    for (int n = 0; n < 7; ++n)
        #pragma unroll
        for (int t = 0; t < 2; ++t) {
            s16x8 bh, bl;
            unpack16(kc + (n * 16 + lr) * 68 + t * 32 + lg * 8, bh, bl);
            #pragma unroll
            for (int im = 0; im < 2; ++im) {
                z[im][n] = mfma16(qhf[im][t], bh, z[im][n]);
                z[im][n] = mfma16(qhf[im][t], bl, z[im][n]);
                z[im][n] = mfma16(qlf[im][t], bh, z[im][n]);
            }
        }
    __builtin_amdgcn_s_setprio(0);

    // ---- uwv = su . v, spread over all waves
    {
        const int d = w * 16 + lr;
        float acc = 0.f;
        #pragma unroll
        for (int c = 0; c < 3; ++c) {
            int k8 = lg + c * 4;
            s16x8 vv = *reinterpret_cast<const s16x8*>(vT + d * 128 + ((k8 ^ (d & 7)) << 3));
            #pragma unroll
            for (int j = 0; j < 8; ++j) acc += subuf[k8 * 8 + j] * bf2f((u16)vv[j]);
        }
        if (lg == 0) {
            s16x8 vv = *reinterpret_cast<const s16x8*>(vT + d * 128 + ((12 ^ (d & 7)) << 3));
            #pragma unroll
            for (int j = 0; j < 8; ++j) acc += subuf[96 + j] * bf2f((u16)vv[j]);
        }
        acc += __shfl_xor(acc, 16, 64);
        acc += __shfl_xor(acc, 32, 64);
        if (lg == 0) uwvb[d] = acc;
    }

    // ---- subtract r_j, mask invalid cols, softmax over k (in-register)
    #pragma unroll
    for (int im = 0; im < 2; ++im) {
        #pragma unroll
        for (int n = 0; n < 7; ++n) {
            float rr = rbuf[n * 16 + lr];
            #pragma unroll
            for (int j = 0; j < 4; ++j) z[im][n][j] -= rr;
        }
        if (lr >= 4) {                         // cols 100..111 invalid
            f32x4 NEG = { -1e30f, -1e30f, -1e30f, -1e30f };
            z[im][6] = NEG;
        }
        #pragma unroll
        for (int j = 0; j < 4; ++j) {
            float m = z[im][0][j];
            #pragma unroll
            for (int n = 1; n < 7; ++n) m = fmaxf(m, z[im][n][j]);
            #pragma unroll
            for (int o = 1; o < 16; o <<= 1) m = fmaxf(m, __shfl_xor(m, o, 16));
            float s = 0.f;
            #pragma unroll
            for (int n = 0; n < 7; ++n) { float p = __expf(z[im][n][j] - m); z[im][n][j] = p; s += p; }
            #pragma unroll
            for (int o = 1; o < 16; o <<= 1) s += __shfl_xor(s, o, 16);
            float inv = 1.f / s;
            #pragma unroll
            for (int n = 0; n < 7; ++n) z[im][n][j] *= inv;
        }
    }
    __syncthreads();                           // B3: all qc/kc reads done (pl aliases qc)

    // ---- write P (bf16); cols 112..127 zeroed
    #pragma unroll
    for (int im = 0; im < 2; ++im) {
        #pragma unroll
        for (int n = 0; n < 7; ++n)
            #pragma unroll
            for (int j = 0; j < 4; ++j) {
                int row = mt[im] * 16 + lg * 4 + j;
                pl[row * 136 + n * 16 + lr] = f2bf(z[im][n][j]);
            }
        #pragma unroll
        for (int j = 0; j < 4; ++j) {
            int row = mt[im] * 16 + lg * 4 + j;
            pl[row * 136 + 112 + lr] = 0;
        }
    }
    __syncthreads();                           // B4: P + vT ready

    // ---- PV (1-term bf16) + epilogue
    s16x8 pa[2][4];
    #pragma unroll
    for (int im = 0; im < 2; ++im)
        #pragma unroll
        for (int t = 0; t < 4; ++t)
            pa[im][t] = *reinterpret_cast<const s16x8*>(pl + (mt[im] * 16 + lr) * 136 + t * 32 + lg * 8);
    f32x4 pv[2][4];
    #pragma unroll
    for (int im = 0; im < 2; ++im)
        #pragma unroll
        for (int n = 0; n < 4; ++n) pv[im][n] = Z4;
    __builtin_amdgcn_s_setprio(1);
    #pragma unroll
    for (int n = 0; n < 4; ++n)
        #pragma unroll
        for (int t = 0; t < 4; ++t) {
            int d = n * 16 + lr;
            s16x8 bv = *reinterpret_cast<const s16x8*>(vT + d * 128 + ((((t * 4 + lg)) ^ (d & 7)) << 3));
            #pragma unroll
            for (int im = 0; im < 2; ++im)
                pv[im][n] = mfma16(pa[im][t], bv, pv[im][n]);
        }
    __builtin_amdgcn_s_setprio(0);

    float bv4[4];
    #pragma unroll
    for (int n = 0; n < 4; ++n) bv4[n] = bres[colb + n * 16 + lr];
    #pragma unroll
    for (int im = 0; im < 2; ++im)
        #pragma unroll
        for (int n = 0; n < 4; ++n) {
            int d = n * 16 + lr;
            float add = bv4[n] + uwvb[d];
            #pragma unroll
            for (int j = 0; j < 4; ++j) {
                int row = mt[im] * 16 + lg * 4 + j;
                if (row < S_)
                    out[((size_t)b * S_ + row) * A_ + colb + d] = ra[im][n][j] + pv[im][n][j] + add;
            }
        }
}

extern "C" void kernel_launch(void* const* d_in, const int* in_sizes, int n_in,
                              void* d_out, int out_size, void* d_ws, size_t ws_size,
                              hipStream_t stream) {
    const float* query = (const float*)d_in[0];
    const float* key   = (const float*)d_in[1];
    const float* value = (const float*)d_in[2];
    const float* Wq    = (const float*)d_in[3];
    const float* Wk    = (const float*)d_in[4];
    const float* Wv    = (const float*)d_in[5];
    const float* Wu    = (const float*)d_in[6];
    const float* Wres  = (const float*)d_in[7];
    const float* bres  = (const float*)d_in[8];
    float* out = (float*)d_out;

    float* su  = (float*)d_ws;                          // 1.6384 MB
    u16*  wbuf = (u16*)((char*)d_ws + 1638400);         // 6 * 64 KB split weights

    prep_kernel<<<1030, 256, 0, stream>>>(key, Wu, Wq, Wk, Wv, Wres, su, wbuf);
    fused6_kernel<<<B_ * H_, 256, 0, stream>>>(query, key, value, bres, su, wbuf, out);
}